// Round 1
// baseline (1161.005 us; speedup 1.0000x reference)
//
#include <hip/hip_runtime.h>
#include <hip/hip_bf16.h>

#define N_NODES 32768
#define E_EDGES 524288
#define HIDDIM 128
#define NHEAD 4
#define FDIM 512      // NHEAD * 128
#define DFF 2048
#define LN_EPS 1e-5f
#define SLOPE 0.2f

// ---------------- tiled fp32 GEMM: C[M,N] = A[M,K] @ B[K,N] (+bias)(+relu) ----------------
template<typename AT, typename OT, bool RELU, bool BIAS>
__global__ __launch_bounds__(256) void gemm_tiled(const AT* __restrict__ A,
                                                  const float* __restrict__ B,
                                                  const float* __restrict__ bias,
                                                  OT* __restrict__ C,
                                                  int M, int N, int K) {
    __shared__ float As[16][68];   // padded: stride 68 breaks bank conflicts, keeps float4 align
    __shared__ float Bs[16][68];
    const int tid = threadIdx.x;
    const int tx = tid & 15, ty = tid >> 4;
    const int row0 = blockIdx.y * 64, col0 = blockIdx.x * 64;
    const int ar = tid >> 2;          // 0..63  (A row within tile)
    const int ac = (tid & 3) * 4;     // 0,4,8,12 (A col within k-tile)
    const int br = tid >> 4;          // 0..15  (B row within k-tile)
    const int bc = (tid & 15) * 4;    // 0..60
    float acc[4][4] = {};
    for (int k0 = 0; k0 < K; k0 += 16) {
        {
            const AT* ap = A + (size_t)(row0 + ar) * K + k0 + ac;
            As[ac + 0][ar] = (float)ap[0];
            As[ac + 1][ar] = (float)ap[1];
            As[ac + 2][ar] = (float)ap[2];
            As[ac + 3][ar] = (float)ap[3];
        }
        {
            const float4 bv = *(const float4*)(B + (size_t)(k0 + br) * N + col0 + bc);
            Bs[br][bc + 0] = bv.x; Bs[br][bc + 1] = bv.y;
            Bs[br][bc + 2] = bv.z; Bs[br][bc + 3] = bv.w;
        }
        __syncthreads();
#pragma unroll
        for (int kk = 0; kk < 16; ++kk) {
            const float4 a = *(const float4*)&As[kk][ty * 4];
            const float4 b = *(const float4*)&Bs[kk][tx * 4];
            acc[0][0] += a.x * b.x; acc[0][1] += a.x * b.y; acc[0][2] += a.x * b.z; acc[0][3] += a.x * b.w;
            acc[1][0] += a.y * b.x; acc[1][1] += a.y * b.y; acc[1][2] += a.y * b.z; acc[1][3] += a.y * b.w;
            acc[2][0] += a.z * b.x; acc[2][1] += a.z * b.y; acc[2][2] += a.z * b.z; acc[2][3] += a.z * b.w;
            acc[3][0] += a.w * b.x; acc[3][1] += a.w * b.y; acc[3][2] += a.w * b.z; acc[3][3] += a.w * b.w;
        }
        __syncthreads();
    }
#pragma unroll
    for (int i = 0; i < 4; ++i) {
        const int r = row0 + ty * 4 + i;
#pragma unroll
        for (int j = 0; j < 4; ++j) {
            const int c = col0 + tx * 4 + j;
            float v = acc[i][j];
            if (BIAS) v += bias[c];
            if (RELU) v = fmaxf(v, 0.f);
            C[(size_t)r * N + c] = (OT)v;
        }
    }
}

// ---------------- el/er per node: dot(ft[n, h*128:...], attn) ----------------
__global__ __launch_bounds__(128) void attn_dots_kernel(const float* __restrict__ ft,
                                                        const float* __restrict__ attn_l,
                                                        const float* __restrict__ attn_r,
                                                        float* __restrict__ el,
                                                        float* __restrict__ er) {
    const int n = blockIdx.x, t = threadIdx.x;
    const float4 f  = ((const float4*)(ft + (size_t)n * FDIM))[t];
    const float4 al = ((const float4*)attn_l)[t];
    const float4 ar = ((const float4*)attn_r)[t];
    float pl = f.x * al.x + f.y * al.y + f.z * al.z + f.w * al.w;
    float pr = f.x * ar.x + f.y * ar.y + f.z * ar.z + f.w * ar.w;
    for (int off = 16; off; off >>= 1) {
        pl += __shfl_down(pl, off, 32);
        pr += __shfl_down(pr, off, 32);
    }
    if ((t & 31) == 0) {
        el[n * 4 + (t >> 5)] = pl;
        er[n * 4 + (t >> 5)] = pr;
    }
}

// ---------------- ce[h] = sum_d W_fe[h*128+d] * attn_e[h*128+d] ----------------
__global__ __launch_bounds__(128) void ce_kernel(const float* __restrict__ W_fe,
                                                 const float* __restrict__ attn_e,
                                                 float* __restrict__ ce) {
    const int t = threadIdx.x;
    const float4 w = ((const float4*)W_fe)[t];
    const float4 a = ((const float4*)attn_e)[t];
    float p = w.x * a.x + w.y * a.y + w.z * a.z + w.w * a.w;
    for (int off = 16; off; off >>= 1) p += __shfl_down(p, off, 32);
    if ((t & 31) == 0) ce[t >> 5] = p;
}

// ---------------- edge pass 1: w = exp(leaky(el[src]+er[dst]+e*ce)); z += w; hist ----------------
__global__ __launch_bounds__(256) void edge_pass1(const float* __restrict__ evals,
                                                  const int* __restrict__ src,
                                                  const int* __restrict__ dst,
                                                  const float* __restrict__ el,
                                                  const float* __restrict__ er,
                                                  const float* __restrict__ ce,
                                                  float* __restrict__ wexp,
                                                  float* __restrict__ z,
                                                  int* __restrict__ counts) {
    const int e = blockIdx.x * 256 + threadIdx.x;
    const int s = src[e], d = dst[e];
    const float ev = evals[e];
    const float4 l = *(const float4*)(el + (size_t)s * 4);
    const float4 r = *(const float4*)(er + (size_t)d * 4);
    const float4 c = *(const float4*)ce;
    float4 w;
    {
        float v;
        v = l.x + r.x + ev * c.x; v = v >= 0.f ? v : SLOPE * v; w.x = expf(v);
        v = l.y + r.y + ev * c.y; v = v >= 0.f ? v : SLOPE * v; w.y = expf(v);
        v = l.z + r.z + ev * c.z; v = v >= 0.f ? v : SLOPE * v; w.z = expf(v);
        v = l.w + r.w + ev * c.w; v = v >= 0.f ? v : SLOPE * v; w.w = expf(v);
    }
    *(float4*)(wexp + (size_t)e * 4) = w;
    atomicAdd(&z[d * 4 + 0], w.x);
    atomicAdd(&z[d * 4 + 1], w.y);
    atomicAdd(&z[d * 4 + 2], w.z);
    atomicAdd(&z[d * 4 + 3], w.w);
    atomicAdd(&counts[d], 1);
}

// ---------------- exclusive scan of counts (N=32768), single block ----------------
__global__ __launch_bounds__(1024) void scan_kernel(const int* __restrict__ counts,
                                                    int* __restrict__ offsets) {
    __shared__ int sums[1024];
    const int t = threadIdx.x;
    const int base = t * 32;
    int local[32];
    int s = 0;
#pragma unroll
    for (int i = 0; i < 32; ++i) { local[i] = s; s += counts[base + i]; }
    sums[t] = s;
    __syncthreads();
    for (int off = 1; off < 1024; off <<= 1) {
        const int v = (t >= off) ? sums[t - off] : 0;
        __syncthreads();
        sums[t] += v;
        __syncthreads();
    }
    const int prefix = (t == 0) ? 0 : sums[t - 1];
#pragma unroll
    for (int i = 0; i < 32; ++i) offsets[base + i] = prefix + local[i];
}

// ---------------- edge pass 2: scatter edge ids into CSR ----------------
__global__ __launch_bounds__(256) void edge_scatter(const int* __restrict__ dst,
                                                    const int* __restrict__ offsets,
                                                    int* __restrict__ cursor,
                                                    int* __restrict__ edge_ids) {
    const int e = blockIdx.x * 256 + threadIdx.x;
    const int d = dst[e];
    const int pos = atomicAdd(&cursor[d], 1);
    edge_ids[offsets[d] + pos] = e;
}

// ---------------- aggregate: rst[n] = sum_e alpha * ft[src]; x1 = relu(rst + res + bias) ----------------
__global__ __launch_bounds__(128) void aggregate_kernel(const float* __restrict__ ft,
                                                        const float* __restrict__ wexp,
                                                        const float* __restrict__ z,
                                                        const int* __restrict__ counts,
                                                        const int* __restrict__ offsets,
                                                        const int* __restrict__ edge_ids,
                                                        const int* __restrict__ src,
                                                        const float* __restrict__ gat_bias,
                                                        float* __restrict__ resx) {
    const int n = blockIdx.x, t = threadIdx.x;
    __shared__ int s_src[128];
    __shared__ float s_w[128][4];
    const float4 zv = *(const float4*)(z + (size_t)n * 4);
    const int ht = t >> 5;
    const float zh = (ht == 0) ? zv.x : (ht == 1) ? zv.y : (ht == 2) ? zv.z : zv.w;
    const float rz = zh > 0.f ? 1.f / zh : 0.f;
    const int deg = counts[n], base = offsets[n];
    float4 acc = {0.f, 0.f, 0.f, 0.f};
    for (int c0 = 0; c0 < deg; c0 += 128) {
        const int i = c0 + t;
        if (i < deg) {
            const int eid = edge_ids[base + i];
            s_src[t] = src[eid];
            *(float4*)s_w[t] = *(const float4*)(wexp + (size_t)eid * 4);
        }
        __syncthreads();
        const int m = min(128, deg - c0);
        for (int j = 0; j < m; ++j) {
            const float alpha = s_w[j][ht] * rz;
            const float4 f = *(const float4*)(ft + (size_t)s_src[j] * FDIM + t * 4);
            acc.x += alpha * f.x; acc.y += alpha * f.y;
            acc.z += alpha * f.z; acc.w += alpha * f.w;
        }
        __syncthreads();
    }
    const float4 r  = *(const float4*)(resx + (size_t)n * FDIM + t * 4);
    const float4 gb = ((const float4*)gat_bias)[t];
    float4 o;
    o.x = fmaxf(acc.x + r.x + gb.x, 0.f);
    o.y = fmaxf(acc.y + r.y + gb.y, 0.f);
    o.z = fmaxf(acc.z + r.z + gb.z, 0.f);
    o.w = fmaxf(acc.w + r.w + gb.w, 0.f);
    *(float4*)(resx + (size_t)n * FDIM + t * 4) = o;
}

// ---------------- LayerNorm over 128 cols: out = LN((relu_x? relu(xin):xin) + add) ----------------
__global__ __launch_bounds__(128) void ln_kernel(const float* __restrict__ xin,
                                                 const float* __restrict__ add,
                                                 const float* __restrict__ g,
                                                 const float* __restrict__ b,
                                                 float* __restrict__ out,
                                                 int relu_x) {
    const int n = blockIdx.x, t = threadIdx.x;
    __shared__ float red[2];
    float x = xin[(size_t)n * HIDDIM + t];
    if (relu_x) x = fmaxf(x, 0.f);
    x += add[(size_t)n * HIDDIM + t];
    float s = x;
    for (int off = 32; off; off >>= 1) s += __shfl_down(s, off, 64);
    if ((t & 63) == 0) red[t >> 6] = s;
    __syncthreads();
    const float mean = (red[0] + red[1]) * (1.f / 128.f);
    const float d = x - mean;
    float q = d * d;
    __syncthreads();
    for (int off = 32; off; off >>= 1) q += __shfl_down(q, off, 64);
    if ((t & 63) == 0) red[t >> 6] = q;
    __syncthreads();
    const float var = (red[0] + red[1]) * (1.f / 128.f);
    out[(size_t)n * HIDDIM + t] = d * rsqrtf(var + LN_EPS) * g[t] + b[t];
}

extern "C" void kernel_launch(void* const* d_in, const int* in_sizes, int n_in,
                              void* d_out, int out_size, void* d_ws, size_t ws_size,
                              hipStream_t stream) {
    const float* h        = (const float*)d_in[0];
    const float* evals    = (const float*)d_in[1];
    const int*   src      = (const int*)d_in[2];
    const int*   dst      = (const int*)d_in[3];
    // d_in[4] = batch_size (unused: flat layout is identical)
    const float* W_fc     = (const float*)d_in[5];
    const float* attn_l   = (const float*)d_in[6];
    const float* attn_r   = (const float*)d_in[7];
    const float* W_fe     = (const float*)d_in[8];
    const float* attn_e   = (const float*)d_in[9];
    const float* W_res    = (const float*)d_in[10];
    const float* gat_bias = (const float*)d_in[11];
    const float* W_mha    = (const float*)d_in[12];
    const float* b_mha    = (const float*)d_in[13];
    const float* n1_g     = (const float*)d_in[14];
    const float* n1_b     = (const float*)d_in[15];
    const float* n2_g     = (const float*)d_in[16];
    const float* n2_b     = (const float*)d_in[17];
    const float* W1       = (const float*)d_in[18];
    const float* b1       = (const float*)d_in[19];
    const float* W2       = (const float*)d_in[20];
    const float* b2       = (const float*)d_in[21];

    char* ws = (char*)d_ws;
    // workspace layout (all 16B-aligned)
    float* ft       = (float*)(ws + 0);                    // 64 MB  N x 512
    float* resx     = (float*)(ws + 67108864ull);          // 64 MB  N x 512 (res, then x1 in place)
    float* x3       = (float*)(ws + 134217728ull);         // 16 MB  N x 128 (post-LN1)
    float* x2       = (float*)(ws + 150994944ull);         // 16 MB  N x 128 scratch
    float* wexp     = (float*)(ws + 167772160ull);         // 8 MB   E x 4
    int*   edge_ids = (int*)  (ws + 176160768ull);         // 2 MB   E
    float* z        = (float*)(ws + 178257920ull);         // 512 KB N x 4
    int*   counts   = (int*)  (ws + 178782208ull);         // 128 KB
    int*   cursor   = (int*)  (ws + 178913280ull);         // 128 KB
    int*   offsets  = (int*)  (ws + 179044352ull);         // 128 KB
    float* el       = (float*)(ws + 179175424ull);         // 512 KB
    float* er       = (float*)(ws + 179699712ull);         // 512 KB
    float* ce       = (float*)(ws + 180224000ull);         // 16 B
    __hip_bfloat16* y = (__hip_bfloat16*)(ws + 0);         // 128 MB N x 2048 bf16, overlays ft+resx (dead by then)

    if (ws_size < 180224064ull) return;  // insufficient workspace -> fail loudly via absmax

    // zero z + counts + cursor (contiguous region)
    hipMemsetAsync(z, 0, 786432, stream);

    dim3 blk(256);
    // ft = h @ W_fc ; res = h @ W_res
    gemm_tiled<float, float, false, false><<<dim3(FDIM / 64, N_NODES / 64), blk, 0, stream>>>(h, W_fc, nullptr, ft, N_NODES, FDIM, HIDDIM);
    gemm_tiled<float, float, false, false><<<dim3(FDIM / 64, N_NODES / 64), blk, 0, stream>>>(h, W_res, nullptr, resx, N_NODES, FDIM, HIDDIM);
    attn_dots_kernel<<<N_NODES, 128, 0, stream>>>(ft, attn_l, attn_r, el, er);
    ce_kernel<<<1, 128, 0, stream>>>(W_fe, attn_e, ce);
    edge_pass1<<<E_EDGES / 256, 256, 0, stream>>>(evals, src, dst, el, er, ce, wexp, z, counts);
    scan_kernel<<<1, 1024, 0, stream>>>(counts, offsets);
    edge_scatter<<<E_EDGES / 256, 256, 0, stream>>>(dst, offsets, cursor, edge_ids);
    aggregate_kernel<<<N_NODES, 128, 0, stream>>>(ft, wexp, z, counts, offsets, edge_ids, src, gat_bias, resx);
    // x2 = x1 @ W_mha + b_mha  (relu folded into LN1)
    gemm_tiled<float, float, false, true><<<dim3(HIDDIM / 64, N_NODES / 64), blk, 0, stream>>>(resx, W_mha, b_mha, x2, N_NODES, HIDDIM, FDIM);
    ln_kernel<<<N_NODES, 128, 0, stream>>>(x2, h, n1_g, n1_b, x3, 1);
    // FFN
    gemm_tiled<float, __hip_bfloat16, true, true><<<dim3(DFF / 64, N_NODES / 64), blk, 0, stream>>>(x3, W1, b1, y, N_NODES, DFF, HIDDIM);
    gemm_tiled<__hip_bfloat16, float, false, true><<<dim3(HIDDIM / 64, N_NODES / 64), blk, 0, stream>>>(y, W2, b2, x2, N_NODES, HIDDIM, DFF);
    ln_kernel<<<N_NODES, 128, 0, stream>>>(x2, x3, n2_g, n2_b, (float*)d_out, 0);
}

// Round 2
// 569.047 us; speedup vs baseline: 2.0403x; 2.0403x over previous
//
#include <hip/hip_runtime.h>
#include <hip/hip_bf16.h>

#define N_NODES 32768
#define E_EDGES 524288
#define HIDDIM 128
#define FDIM 512
#define DFF 2048
#define LN_EPS 1e-5f
#define SLOPE 0.2f

typedef __bf16 bf16_t;
typedef __bf16 bf16x8 __attribute__((ext_vector_type(8)));
typedef float f32x4 __attribute__((ext_vector_type(4)));

#define GLD_LDS16(gp, lp) __builtin_amdgcn_global_load_lds( \
    (const __attribute__((address_space(1))) unsigned int*)(gp), \
    (__attribute__((address_space(3))) unsigned int*)(lp), 16, 0, 0)

// ============ bf16 MFMA GEMM: C[M,N] = A[M,K] @ B[K,N] ============
// A: row-major bf16. Bp: k8-packed bf16: Bp[((k/8)*N + n)*8 + j] = B[(k/8)*8+j][n].
// 128x128 block tile, 4 waves in 2x2 of 64x64, BK=32.
template<typename OT, bool RELU, bool BIAS>
__global__ __launch_bounds__(256) void gemm_mfma(const bf16_t* __restrict__ A,
                                                 const bf16_t* __restrict__ Bp,
                                                 const float* __restrict__ bias,
                                                 OT* __restrict__ C,
                                                 int M, int N, int K) {
    __shared__ __align__(16) bf16_t lA[4096];   // 8KB: chunk c=(g*128+m), 8 bf16 each
    __shared__ __align__(16) bf16_t lB[4096];   // 8KB: chunk c=(g*128+n)
    const int tid = threadIdx.x;
    const int lane = tid & 63;
    const int wave = tid >> 6;
    const int wm = (wave >> 1) * 64, wn = (wave & 1) * 64;
    const int row0 = blockIdx.y * 128, col0 = blockIdx.x * 128;
    const int ko = lane >> 4;       // k-group 0..3
    const int rl = lane & 15;
    f32x4 acc[4][4] = {};

    const int c0 = tid, c1 = tid + 256;
    const int g0 = c0 >> 7, m0 = c0 & 127;
    const int g1 = c1 >> 7, m1 = c1 & 127;

    for (int k0 = 0; k0 < K; k0 += 32) {
        __syncthreads();
        // stage A (row-major): 16B = 8 bf16 at (row0+m)*K + k0 + g*8
        GLD_LDS16(A + (size_t)(row0 + m0) * K + k0 + g0 * 8, lA + c0 * 8);
        GLD_LDS16(A + (size_t)(row0 + m1) * K + k0 + g1 * 8, lA + c1 * 8);
        // stage B (k8-packed): contiguous
        GLD_LDS16(Bp + ((size_t)(k0 / 8 + g0) * N + col0 + m0) * 8, lB + c0 * 8);
        GLD_LDS16(Bp + ((size_t)(k0 / 8 + g1) * N + col0 + m1) * 8, lB + c1 * 8);
        __syncthreads();
        bf16x8 af[4], bfr[4];
#pragma unroll
        for (int i = 0; i < 4; ++i) {
            af[i]  = *(const bf16x8*)&lA[(ko * 128 + wm + i * 16 + rl) * 8];
            bfr[i] = *(const bf16x8*)&lB[(ko * 128 + wn + i * 16 + rl) * 8];
        }
#pragma unroll
        for (int i = 0; i < 4; ++i)
#pragma unroll
            for (int j = 0; j < 4; ++j)
                acc[i][j] = __builtin_amdgcn_mfma_f32_16x16x32_bf16(af[i], bfr[j], acc[i][j], 0, 0, 0);
    }
    const int cr = (lane >> 4) * 4;
    const int cc = lane & 15;
#pragma unroll
    for (int i = 0; i < 4; ++i)
#pragma unroll
        for (int j = 0; j < 4; ++j) {
            const int col = col0 + wn + j * 16 + cc;
            float bv = BIAS ? bias[col] : 0.f;
#pragma unroll
            for (int r = 0; r < 4; ++r) {
                const int row = row0 + wm + i * 16 + cr + r;
                float v = acc[i][j][r] + bv;
                if (RELU) v = fmaxf(v, 0.f);
                C[(size_t)row * N + col] = (OT)v;
            }
        }
}

// ============ weight packing: fp32 [K][N] -> k8-packed bf16 ============
__global__ __launch_bounds__(256) void pack_b(const float* __restrict__ B, bf16_t* __restrict__ out,
                                              int K8, int N) {
    const int id = blockIdx.x * 256 + threadIdx.x;
    if (id >= K8 * N) return;
    const int g = id / N, n = id % N;
    union { bf16_t b[8]; uint4 u; } pk;
#pragma unroll
    for (int j = 0; j < 8; ++j) pk.b[j] = (bf16_t)B[(size_t)(g * 8 + j) * N + n];
    *(uint4*)(out + (size_t)id * 8) = pk.u;
}

// pack concat(W_fc, W_res) horizontally: K=128, each N=512 -> N=1024
__global__ __launch_bounds__(256) void pack_cat(const float* __restrict__ B0, const float* __restrict__ B1,
                                                bf16_t* __restrict__ out) {
    const int id = blockIdx.x * 256 + threadIdx.x;  // g*1024 + n, g<16
    if (id >= 16 * 1024) return;
    const int g = id >> 10, n = id & 1023;
    const float* B = (n < 512) ? B0 : B1;
    const int nn = n & 511;
    union { bf16_t b[8]; uint4 u; } pk;
#pragma unroll
    for (int j = 0; j < 8; ++j) pk.b[j] = (bf16_t)B[(size_t)(g * 8 + j) * 512 + nn];
    *(uint4*)(out + (size_t)id * 8) = pk.u;
}

// ============ fp32 -> bf16 elementwise (h) ============
__global__ __launch_bounds__(256) void f2b_kernel(const float* __restrict__ x, bf16_t* __restrict__ o) {
    const int id = blockIdx.x * 256 + threadIdx.x;   // covers 4 elems
    const float4 v = ((const float4*)x)[id];
    union { bf16_t b[4]; uint2 u; } pk;
    pk.b[0] = (bf16_t)v.x; pk.b[1] = (bf16_t)v.y; pk.b[2] = (bf16_t)v.z; pk.b[3] = (bf16_t)v.w;
    *(uint2*)(o + (size_t)id * 4) = pk.u;
}

// ============ el/er: dots of ftres (bf16, stride 1024) with attn vecs ============
__global__ __launch_bounds__(128) void attn_dots_kernel(const bf16_t* __restrict__ ftres,
                                                        const float* __restrict__ attn_l,
                                                        const float* __restrict__ attn_r,
                                                        float* __restrict__ el,
                                                        float* __restrict__ er) {
    const int n = blockIdx.x, t = threadIdx.x;
    const uint2 u = *(const uint2*)(ftres + (size_t)n * 1024 + t * 4);
    const float f0 = __uint_as_float(u.x << 16), f1 = __uint_as_float(u.x & 0xFFFF0000u);
    const float f2 = __uint_as_float(u.y << 16), f3 = __uint_as_float(u.y & 0xFFFF0000u);
    const float4 al = ((const float4*)attn_l)[t];
    const float4 ar = ((const float4*)attn_r)[t];
    float pl = f0 * al.x + f1 * al.y + f2 * al.z + f3 * al.w;
    float pr = f0 * ar.x + f1 * ar.y + f2 * ar.z + f3 * ar.w;
    for (int off = 16; off; off >>= 1) {
        pl += __shfl_down(pl, off, 32);
        pr += __shfl_down(pr, off, 32);
    }
    if ((t & 31) == 0) {
        el[n * 4 + (t >> 5)] = pl;
        er[n * 4 + (t >> 5)] = pr;
    }
}

__global__ __launch_bounds__(128) void ce_kernel(const float* __restrict__ W_fe,
                                                 const float* __restrict__ attn_e,
                                                 float* __restrict__ ce) {
    const int t = threadIdx.x;
    const float4 w = ((const float4*)W_fe)[t];
    const float4 a = ((const float4*)attn_e)[t];
    float p = w.x * a.x + w.y * a.y + w.z * a.z + w.w * a.w;
    for (int off = 16; off; off >>= 1) p += __shfl_down(p, off, 32);
    if ((t & 31) == 0) ce[t >> 5] = p;
}

__global__ __launch_bounds__(256) void edge_pass1(const float* __restrict__ evals,
                                                  const int* __restrict__ src,
                                                  const int* __restrict__ dst,
                                                  const float* __restrict__ el,
                                                  const float* __restrict__ er,
                                                  const float* __restrict__ ce,
                                                  float* __restrict__ wexp,
                                                  float* __restrict__ z,
                                                  int* __restrict__ counts) {
    const int e = blockIdx.x * 256 + threadIdx.x;
    const int s = src[e], d = dst[e];
    const float ev = evals[e];
    const float4 l = *(const float4*)(el + (size_t)s * 4);
    const float4 r = *(const float4*)(er + (size_t)d * 4);
    const float4 c = *(const float4*)ce;
    float4 w;
    {
        float v;
        v = l.x + r.x + ev * c.x; v = v >= 0.f ? v : SLOPE * v; w.x = expf(v);
        v = l.y + r.y + ev * c.y; v = v >= 0.f ? v : SLOPE * v; w.y = expf(v);
        v = l.z + r.z + ev * c.z; v = v >= 0.f ? v : SLOPE * v; w.z = expf(v);
        v = l.w + r.w + ev * c.w; v = v >= 0.f ? v : SLOPE * v; w.w = expf(v);
    }
    *(float4*)(wexp + (size_t)e * 4) = w;
    atomicAdd(&z[d * 4 + 0], w.x);
    atomicAdd(&z[d * 4 + 1], w.y);
    atomicAdd(&z[d * 4 + 2], w.z);
    atomicAdd(&z[d * 4 + 3], w.w);
    atomicAdd(&counts[d], 1);
}

__global__ __launch_bounds__(1024) void scan_kernel(const int* __restrict__ counts,
                                                    int* __restrict__ offsets) {
    __shared__ int sums[1024];
    const int t = threadIdx.x;
    const int base = t * 32;
    int local[32];
    int s = 0;
#pragma unroll
    for (int i = 0; i < 32; ++i) { local[i] = s; s += counts[base + i]; }
    sums[t] = s;
    __syncthreads();
    for (int off = 1; off < 1024; off <<= 1) {
        const int v = (t >= off) ? sums[t - off] : 0;
        __syncthreads();
        sums[t] += v;
        __syncthreads();
    }
    const int prefix = (t == 0) ? 0 : sums[t - 1];
#pragma unroll
    for (int i = 0; i < 32; ++i) offsets[base + i] = prefix + local[i];
}

__global__ __launch_bounds__(256) void edge_scatter(const int* __restrict__ dst,
                                                    const int* __restrict__ offsets,
                                                    int* __restrict__ cursor,
                                                    int* __restrict__ edge_ids) {
    const int e = blockIdx.x * 256 + threadIdx.x;
    const int d = dst[e];
    const int pos = atomicAdd(&cursor[d], 1);
    edge_ids[offsets[d] + pos] = e;
}

// ============ aggregate over CSR: x1 = relu(sum alpha*ft[src] + res + bias), bf16 out ============
__global__ __launch_bounds__(128) void aggregate_kernel(const bf16_t* __restrict__ ftres,
                                                        const float* __restrict__ wexp,
                                                        const float* __restrict__ z,
                                                        const int* __restrict__ counts,
                                                        const int* __restrict__ offsets,
                                                        const int* __restrict__ edge_ids,
                                                        const int* __restrict__ src,
                                                        const float* __restrict__ gat_bias,
                                                        bf16_t* __restrict__ x1) {
    const int n = blockIdx.x, t = threadIdx.x;
    __shared__ int s_src[128];
    __shared__ float s_w[128][4];
    const float4 zv = *(const float4*)(z + (size_t)n * 4);
    const int ht = t >> 5;
    const float zh = (ht == 0) ? zv.x : (ht == 1) ? zv.y : (ht == 2) ? zv.z : zv.w;
    const float rz = zh > 0.f ? 1.f / zh : 0.f;
    const int deg = counts[n], base = offsets[n];
    float4 acc = {0.f, 0.f, 0.f, 0.f};
    for (int c0 = 0; c0 < deg; c0 += 128) {
        const int i = c0 + t;
        if (i < deg) {
            const int eid = edge_ids[base + i];
            s_src[t] = src[eid];
            *(float4*)s_w[t] = *(const float4*)(wexp + (size_t)eid * 4);
        }
        __syncthreads();
        const int m = min(128, deg - c0);
        for (int j = 0; j < m; ++j) {
            const float alpha = s_w[j][ht] * rz;
            const uint2 u = *(const uint2*)(ftres + (size_t)s_src[j] * 1024 + t * 4);
            acc.x += alpha * __uint_as_float(u.x << 16);
            acc.y += alpha * __uint_as_float(u.x & 0xFFFF0000u);
            acc.z += alpha * __uint_as_float(u.y << 16);
            acc.w += alpha * __uint_as_float(u.y & 0xFFFF0000u);
        }
        __syncthreads();
    }
    const uint2 ur = *(const uint2*)(ftres + (size_t)n * 1024 + 512 + t * 4);
    const float4 gb = ((const float4*)gat_bias)[t];
    union { bf16_t b[4]; uint2 u; } pk;
    pk.b[0] = (bf16_t)fmaxf(acc.x + __uint_as_float(ur.x << 16) + gb.x, 0.f);
    pk.b[1] = (bf16_t)fmaxf(acc.y + __uint_as_float(ur.x & 0xFFFF0000u) + gb.y, 0.f);
    pk.b[2] = (bf16_t)fmaxf(acc.z + __uint_as_float(ur.y << 16) + gb.z, 0.f);
    pk.b[3] = (bf16_t)fmaxf(acc.w + __uint_as_float(ur.y & 0xFFFF0000u) + gb.w, 0.f);
    *(uint2*)(x1 + (size_t)n * 512 + t * 4) = pk.u;
}

// ============ LayerNorm over 128: out = LN((relu? relu(xin):xin) + add) ============
template<bool RELUX, typename ADDT, typename OUTT>
__global__ __launch_bounds__(128) void ln_kernel(const float* __restrict__ xin,
                                                 const ADDT* __restrict__ add,
                                                 const float* __restrict__ g,
                                                 const float* __restrict__ b,
                                                 OUTT* __restrict__ out) {
    const int n = blockIdx.x, t = threadIdx.x;
    __shared__ float red[2];
    float x = xin[(size_t)n * HIDDIM + t];
    if (RELUX) x = fmaxf(x, 0.f);
    x += (float)add[(size_t)n * HIDDIM + t];
    float s = x;
    for (int off = 32; off; off >>= 1) s += __shfl_down(s, off, 64);
    if ((t & 63) == 0) red[t >> 6] = s;
    __syncthreads();
    const float mean = (red[0] + red[1]) * (1.f / 128.f);
    const float d = x - mean;
    float q = d * d;
    __syncthreads();
    for (int off = 32; off; off >>= 1) q += __shfl_down(q, off, 64);
    if ((t & 63) == 0) red[t >> 6] = q;
    __syncthreads();
    const float var = (red[0] + red[1]) * (1.f / 128.f);
    out[(size_t)n * HIDDIM + t] = (OUTT)(d * rsqrtf(var + LN_EPS) * g[t] + b[t]);
}

extern "C" void kernel_launch(void* const* d_in, const int* in_sizes, int n_in,
                              void* d_out, int out_size, void* d_ws, size_t ws_size,
                              hipStream_t stream) {
    const float* h        = (const float*)d_in[0];
    const float* evals    = (const float*)d_in[1];
    const int*   src      = (const int*)d_in[2];
    const int*   dst      = (const int*)d_in[3];
    const float* W_fc     = (const float*)d_in[5];
    const float* attn_l   = (const float*)d_in[6];
    const float* attn_r   = (const float*)d_in[7];
    const float* W_fe     = (const float*)d_in[8];
    const float* attn_e   = (const float*)d_in[9];
    const float* W_res    = (const float*)d_in[10];
    const float* gat_bias = (const float*)d_in[11];
    const float* W_mha    = (const float*)d_in[12];
    const float* b_mha    = (const float*)d_in[13];
    const float* n1_g     = (const float*)d_in[14];
    const float* n1_b     = (const float*)d_in[15];
    const float* n2_g     = (const float*)d_in[16];
    const float* n2_b     = (const float*)d_in[17];
    const float* W1       = (const float*)d_in[18];
    const float* b1       = (const float*)d_in[19];
    const float* W2       = (const float*)d_in[20];
    const float* b2       = (const float*)d_in[21];

    char* ws = (char*)d_ws;
    // layout (bytes); region [0,134217728) is reused by y after its tenants die
    bf16_t* ftres   = (bf16_t*)(ws + 0);            // 64MB  N x 1024 (ft | res)
    bf16_t* x1      = (bf16_t*)(ws + 67108864ull);  // 32MB  N x 512
    float*  wexp    = (float*) (ws + 100663296ull); // 8MB   E x 4
    int*    edge_ids= (int*)   (ws + 109051904ull); // 2MB
    bf16_t* hb      = (bf16_t*)(ws + 111149056ull); // 8MB   N x 128
    bf16_t* y       = (bf16_t*)(ws + 0);            // 128MB N x 2048 (overlay; all above dead)
    float*  x2      = (float*) (ws + 134217728ull); // 16MB  N x 128
    bf16_t* x3b     = (bf16_t*)(ws + 150994944ull); // 8MB   N x 128
    bf16_t* Wcat_p  = (bf16_t*)(ws + 159383552ull); // 256KB 16x1024x8
    bf16_t* Wmha_p  = (bf16_t*)(ws + 159645696ull); // 128KB 64x128x8
    bf16_t* W1_p    = (bf16_t*)(ws + 159776768ull); // 512KB 16x2048x8
    bf16_t* W2_p    = (bf16_t*)(ws + 160301056ull); // 512KB 256x128x8
    float*  z       = (float*) (ws + 160825344ull); // 512KB
    int*    counts  = (int*)   (ws + 161349632ull); // 128KB
    int*    cursor  = (int*)   (ws + 161480704ull); // 128KB
    int*    offsets = (int*)   (ws + 161611776ull); // 128KB
    float*  el      = (float*) (ws + 161742848ull); // 512KB
    float*  er      = (float*) (ws + 162267136ull); // 512KB
    float*  ce      = (float*) (ws + 162791424ull); // 16B

    if (ws_size < 180224064ull) return;

    hipMemsetAsync(z, 0, 786432, stream);  // z + counts + cursor

    // conversions / packing
    f2b_kernel<<<4096, 256, 0, stream>>>(h, hb);
    pack_cat<<<64, 256, 0, stream>>>(W_fc, W_res, Wcat_p);
    pack_b<<<32, 256, 0, stream>>>(W_mha, Wmha_p, 64, 128);
    pack_b<<<128, 256, 0, stream>>>(W1, W1_p, 16, 2048);
    pack_b<<<128, 256, 0, stream>>>(W2, W2_p, 256, 128);

    // ftres = hb @ [W_fc | W_res]
    gemm_mfma<bf16_t, false, false><<<dim3(8, 256), 256, 0, stream>>>(hb, Wcat_p, nullptr, ftres, N_NODES, 1024, 128);
    attn_dots_kernel<<<N_NODES, 128, 0, stream>>>(ftres, attn_l, attn_r, el, er);
    ce_kernel<<<1, 128, 0, stream>>>(W_fe, attn_e, ce);
    edge_pass1<<<E_EDGES / 256, 256, 0, stream>>>(evals, src, dst, el, er, ce, wexp, z, counts);
    scan_kernel<<<1, 1024, 0, stream>>>(counts, offsets);
    edge_scatter<<<E_EDGES / 256, 256, 0, stream>>>(dst, offsets, cursor, edge_ids);
    aggregate_kernel<<<N_NODES, 128, 0, stream>>>(ftres, wexp, z, counts, offsets, edge_ids, src, gat_bias, x1);
    // x2 = x1 @ W_mha + b_mha
    gemm_mfma<float, false, true><<<dim3(1, 256), 256, 0, stream>>>(x1, Wmha_p, b_mha, x2, N_NODES, 128, 512);
    ln_kernel<true, float, bf16_t><<<N_NODES, 128, 0, stream>>>(x2, h, n1_g, n1_b, x3b);
    // FFN
    gemm_mfma<bf16_t, true, true><<<dim3(16, 256), 256, 0, stream>>>(x3b, W1_p, b1, y, N_NODES, DFF, 128);
    gemm_mfma<float, false, true><<<dim3(1, 256), 256, 0, stream>>>(y, W2_p, b2, x2, N_NODES, 128, DFF);
    ln_kernel<false, bf16_t, float><<<N_NODES, 128, 0, stream>>>(x2, x3b, n2_g, n2_b, (float*)d_out);
}

// Round 3
// 421.606 us; speedup vs baseline: 2.7538x; 1.3497x over previous
//
#include <hip/hip_runtime.h>
#include <hip/hip_bf16.h>

#define N_NODES 32768
#define E_EDGES 524288
#define HIDDIM 128
#define FDIM 512
#define DFF 2048
#define LN_EPS 1e-5f
#define SLOPE 0.2f
#define CAP 64          // CSR slot capacity per dst node (Poisson(16): P(>64) ~ 1e-19)

typedef __bf16 bf16_t;
typedef __bf16 bf16x8 __attribute__((ext_vector_type(8)));
typedef float f32x4 __attribute__((ext_vector_type(4)));

#define GLD_LDS16(gp, lp) __builtin_amdgcn_global_load_lds( \
    (const __attribute__((address_space(1))) unsigned int*)(gp), \
    (__attribute__((address_space(3))) unsigned int*)(lp), 16, 0, 0)

// ============ bf16 MFMA GEMM: C[M,N] = A[M,K] @ Bp (+bias)(+relu) ============
// A row-major bf16. Bp k8-packed: Bp[((k/8)*N + n)*8 + j] = B[(k/8)*8+j][n].
// 128x128 tile, 4 waves 2x2 of 64x64, BK=32.
template<typename OT, bool RELU, bool BIAS>
__global__ __launch_bounds__(256) void gemm_mfma(const bf16_t* __restrict__ A,
                                                 const bf16_t* __restrict__ Bp,
                                                 const float* __restrict__ bias,
                                                 OT* __restrict__ C,
                                                 int M, int N, int K) {
    __shared__ __align__(16) bf16_t lA[4096];
    __shared__ __align__(16) bf16_t lB[4096];
    const int tid = threadIdx.x;
    const int lane = tid & 63;
    const int wave = tid >> 6;
    const int wm = (wave >> 1) * 64, wn = (wave & 1) * 64;
    const int row0 = blockIdx.y * 128, col0 = blockIdx.x * 128;
    const int ko = lane >> 4;
    const int rl = lane & 15;
    f32x4 acc[4][4] = {};
    const int c0 = tid, c1 = tid + 256;
    const int g0 = c0 >> 7, m0 = c0 & 127;
    const int g1 = c1 >> 7, m1 = c1 & 127;
    for (int k0 = 0; k0 < K; k0 += 32) {
        __syncthreads();
        GLD_LDS16(A + (size_t)(row0 + m0) * K + k0 + g0 * 8, lA + c0 * 8);
        GLD_LDS16(A + (size_t)(row0 + m1) * K + k0 + g1 * 8, lA + c1 * 8);
        GLD_LDS16(Bp + ((size_t)(k0 / 8 + g0) * N + col0 + m0) * 8, lB + c0 * 8);
        GLD_LDS16(Bp + ((size_t)(k0 / 8 + g1) * N + col0 + m1) * 8, lB + c1 * 8);
        __syncthreads();
        bf16x8 af[4], bfr[4];
#pragma unroll
        for (int i = 0; i < 4; ++i) {
            af[i]  = *(const bf16x8*)&lA[(ko * 128 + wm + i * 16 + rl) * 8];
            bfr[i] = *(const bf16x8*)&lB[(ko * 128 + wn + i * 16 + rl) * 8];
        }
#pragma unroll
        for (int i = 0; i < 4; ++i)
#pragma unroll
            for (int j = 0; j < 4; ++j)
                acc[i][j] = __builtin_amdgcn_mfma_f32_16x16x32_bf16(af[i], bfr[j], acc[i][j], 0, 0, 0);
    }
    const int cr = (lane >> 4) * 4;
    const int cc = lane & 15;
#pragma unroll
    for (int i = 0; i < 4; ++i)
#pragma unroll
        for (int j = 0; j < 4; ++j) {
            const int col = col0 + wn + j * 16 + cc;
            float bv = BIAS ? bias[col] : 0.f;
#pragma unroll
            for (int r = 0; r < 4; ++r) {
                const int row = row0 + wm + i * 16 + cr + r;
                float v = acc[i][j][r] + bv;
                if (RELU) v = fmaxf(v, 0.f);
                C[(size_t)row * N + col] = (OT)v;
            }
        }
}

// ============ weight packing: fp32 [K][N] -> k8-packed bf16 ============
__global__ __launch_bounds__(256) void pack_b(const float* __restrict__ B, bf16_t* __restrict__ out,
                                              int K8, int N) {
    const int id = blockIdx.x * 256 + threadIdx.x;
    if (id >= K8 * N) return;
    const int g = id / N, n = id % N;
    union { bf16_t b[8]; uint4 u; } pk;
#pragma unroll
    for (int j = 0; j < 8; ++j) pk.b[j] = (bf16_t)B[(size_t)(g * 8 + j) * N + n];
    *(uint4*)(out + (size_t)id * 8) = pk.u;
}

__global__ __launch_bounds__(256) void f2b_kernel(const float* __restrict__ x, bf16_t* __restrict__ o) {
    const int id = blockIdx.x * 256 + threadIdx.x;
    const float4 v = ((const float4*)x)[id];
    union { bf16_t b[4]; uint2 u; } pk;
    pk.b[0] = (bf16_t)v.x; pk.b[1] = (bf16_t)v.y; pk.b[2] = (bf16_t)v.z; pk.b[3] = (bf16_t)v.w;
    *(uint2*)(o + (size_t)id * 4) = pk.u;
}

// ============ el/er: dots of ft (bf16, stride 512) with attn vecs ============
__global__ __launch_bounds__(128) void attn_dots_kernel(const bf16_t* __restrict__ ft,
                                                        const float* __restrict__ attn_l,
                                                        const float* __restrict__ attn_r,
                                                        float* __restrict__ el,
                                                        float* __restrict__ er) {
    const int n = blockIdx.x, t = threadIdx.x;
    const uint2 u = *(const uint2*)(ft + (size_t)n * FDIM + t * 4);
    const float f0 = __uint_as_float(u.x << 16), f1 = __uint_as_float(u.x & 0xFFFF0000u);
    const float f2 = __uint_as_float(u.y << 16), f3 = __uint_as_float(u.y & 0xFFFF0000u);
    const float4 al = ((const float4*)attn_l)[t];
    const float4 ar = ((const float4*)attn_r)[t];
    float pl = f0 * al.x + f1 * al.y + f2 * al.z + f3 * al.w;
    float pr = f0 * ar.x + f1 * ar.y + f2 * ar.z + f3 * ar.w;
    for (int off = 16; off; off >>= 1) {
        pl += __shfl_down(pl, off, 32);
        pr += __shfl_down(pr, off, 32);
    }
    if ((t & 31) == 0) {
        el[n * 4 + (t >> 5)] = pl;
        er[n * 4 + (t >> 5)] = pr;
    }
}

__global__ __launch_bounds__(128) void ce_kernel(const float* __restrict__ W_fe,
                                                 const float* __restrict__ attn_e,
                                                 float* __restrict__ ce) {
    const int t = threadIdx.x;
    const float4 w = ((const float4*)W_fe)[t];
    const float4 a = ((const float4*)attn_e)[t];
    float p = w.x * a.x + w.y * a.y + w.z * a.z + w.w * a.w;
    for (int off = 16; off; off >>= 1) p += __shfl_down(p, off, 32);
    if ((t & 31) == 0) ce[t >> 5] = p;
}

// ============ edge build: compute w = exp(leaky(score)) and scatter into CSR slots ============
__global__ __launch_bounds__(256) void edge_build(const float* __restrict__ evals,
                                                  const int* __restrict__ src,
                                                  const int* __restrict__ dst,
                                                  const float* __restrict__ el,
                                                  const float* __restrict__ er,
                                                  const float* __restrict__ ce,
                                                  int* __restrict__ cursor,
                                                  int* __restrict__ csr_src,
                                                  float4* __restrict__ csr_w) {
    const int e = blockIdx.x * 256 + threadIdx.x;
    const int s = src[e], d = dst[e];
    const float ev = evals[e];
    const float4 l = *(const float4*)(el + (size_t)s * 4);
    const float4 r = *(const float4*)(er + (size_t)d * 4);
    const float4 c = *(const float4*)ce;
    float4 w;
    {
        float v;
        v = l.x + r.x + ev * c.x; v = v >= 0.f ? v : SLOPE * v; w.x = expf(v);
        v = l.y + r.y + ev * c.y; v = v >= 0.f ? v : SLOPE * v; w.y = expf(v);
        v = l.z + r.z + ev * c.z; v = v >= 0.f ? v : SLOPE * v; w.z = expf(v);
        v = l.w + r.w + ev * c.w; v = v >= 0.f ? v : SLOPE * v; w.w = expf(v);
    }
    const int pos = atomicAdd(&cursor[d], 1);
    if (pos < CAP) {
        csr_src[(size_t)d * CAP + pos] = s;
        csr_w[(size_t)d * CAP + pos] = w;
    }
}

// ============ aggregate: x1 = relu((Σ w*ft[src])/Σw + res + bias), bf16 out ============
__global__ __launch_bounds__(128) void aggregate_kernel(const bf16_t* __restrict__ ft,
                                                        const bf16_t* __restrict__ res,
                                                        const int* __restrict__ cursor,
                                                        const int* __restrict__ csr_src,
                                                        const float4* __restrict__ csr_w,
                                                        const float* __restrict__ gat_bias,
                                                        bf16_t* __restrict__ x1) {
    const int n = blockIdx.x, t = threadIdx.x;
    __shared__ int s_src[CAP];
    __shared__ float s_w[CAP][4];
    const int deg = min(cursor[n], CAP);
    const int ht = t >> 5;
    if (t < deg) {
        s_src[t] = csr_src[(size_t)n * CAP + t];
        *(float4*)s_w[t] = csr_w[(size_t)n * CAP + t];
    }
    __syncthreads();
    float4 acc = {0.f, 0.f, 0.f, 0.f};
    float z = 0.f;
    for (int j = 0; j < deg; ++j) {
        const float w = s_w[j][ht];
        z += w;
        const uint2 u = *(const uint2*)(ft + (size_t)s_src[j] * FDIM + t * 4);
        acc.x += w * __uint_as_float(u.x << 16);
        acc.y += w * __uint_as_float(u.x & 0xFFFF0000u);
        acc.z += w * __uint_as_float(u.y << 16);
        acc.w += w * __uint_as_float(u.y & 0xFFFF0000u);
    }
    const float rz = deg > 0 ? 1.f / z : 0.f;
    const uint2 ur = *(const uint2*)(res + (size_t)n * FDIM + t * 4);
    const float4 gb = ((const float4*)gat_bias)[t];
    union { bf16_t b[4]; uint2 u; } pk;
    pk.b[0] = (bf16_t)fmaxf(acc.x * rz + __uint_as_float(ur.x << 16) + gb.x, 0.f);
    pk.b[1] = (bf16_t)fmaxf(acc.y * rz + __uint_as_float(ur.x & 0xFFFF0000u) + gb.y, 0.f);
    pk.b[2] = (bf16_t)fmaxf(acc.z * rz + __uint_as_float(ur.y << 16) + gb.z, 0.f);
    pk.b[3] = (bf16_t)fmaxf(acc.w * rz + __uint_as_float(ur.y & 0xFFFF0000u) + gb.w, 0.f);
    *(uint2*)(x1 + (size_t)n * FDIM + t * 4) = pk.u;
}

// ============ LayerNorm over 128: out = LN((relu? relu(xin):xin) + add) ============
template<bool RELUX, typename ADDT, typename OUTT>
__global__ __launch_bounds__(128) void ln_kernel(const float* __restrict__ xin,
                                                 const ADDT* __restrict__ add,
                                                 const float* __restrict__ g,
                                                 const float* __restrict__ b,
                                                 OUTT* __restrict__ out) {
    const int n = blockIdx.x, t = threadIdx.x;
    __shared__ float red[2];
    float x = xin[(size_t)n * HIDDIM + t];
    if (RELUX) x = fmaxf(x, 0.f);
    x += (float)add[(size_t)n * HIDDIM + t];
    float s = x;
    for (int off = 32; off; off >>= 1) s += __shfl_down(s, off, 64);
    if ((t & 63) == 0) red[t >> 6] = s;
    __syncthreads();
    const float mean = (red[0] + red[1]) * (1.f / 128.f);
    const float d = x - mean;
    float q = d * d;
    __syncthreads();
    for (int off = 32; off; off >>= 1) q += __shfl_down(q, off, 64);
    if ((t & 63) == 0) red[t >> 6] = q;
    __syncthreads();
    const float var = (red[0] + red[1]) * (1.f / 128.f);
    out[(size_t)n * HIDDIM + t] = (OUTT)(d * rsqrtf(var + LN_EPS) * g[t] + b[t]);
}

extern "C" void kernel_launch(void* const* d_in, const int* in_sizes, int n_in,
                              void* d_out, int out_size, void* d_ws, size_t ws_size,
                              hipStream_t stream) {
    const float* h        = (const float*)d_in[0];
    const float* evals    = (const float*)d_in[1];
    const int*   src      = (const int*)d_in[2];
    const int*   dst      = (const int*)d_in[3];
    const float* W_fc     = (const float*)d_in[5];
    const float* attn_l   = (const float*)d_in[6];
    const float* attn_r   = (const float*)d_in[7];
    const float* W_fe     = (const float*)d_in[8];
    const float* attn_e   = (const float*)d_in[9];
    const float* W_res    = (const float*)d_in[10];
    const float* gat_bias = (const float*)d_in[11];
    const float* W_mha    = (const float*)d_in[12];
    const float* b_mha    = (const float*)d_in[13];
    const float* n1_g     = (const float*)d_in[14];
    const float* n1_b     = (const float*)d_in[15];
    const float* n2_g     = (const float*)d_in[16];
    const float* n2_b     = (const float*)d_in[17];
    const float* W1       = (const float*)d_in[18];
    const float* b1       = (const float*)d_in[19];
    const float* W2       = (const float*)d_in[20];
    const float* b2       = (const float*)d_in[21];

    char* ws = (char*)d_ws;
    bf16_t* ft      = (bf16_t*)(ws + 0);             // 32MB  N x 512
    bf16_t* res     = (bf16_t*)(ws + 33554432ull);   // 32MB  N x 512
    bf16_t* x1      = (bf16_t*)(ws + 67108864ull);   // 32MB  N x 512
    float4* csr_w   = (float4*)(ws + 100663296ull);  // 32MB  N x CAP x 16B
    bf16_t* y       = (bf16_t*)(ws + 0);             // 128MB N x 2048 (overlay; above all dead by FFN1)
    float*  x2      = (float*) (ws + 134217728ull);  // 16MB  N x 128
    bf16_t* x3b     = (bf16_t*)(ws + 150994944ull);  // 8MB   N x 128
    bf16_t* hb      = (bf16_t*)(ws + 159383552ull);  // 8MB   N x 128
    int*    csr_src = (int*)   (ws + 167772160ull);  // 8MB   N x CAP
    bf16_t* Wfc_p   = (bf16_t*)(ws + 176160768ull);  // 128KB
    bf16_t* Wres_p  = (bf16_t*)(ws + 176291840ull);  // 128KB
    bf16_t* Wmha_p  = (bf16_t*)(ws + 176422912ull);  // 128KB
    bf16_t* W1_p    = (bf16_t*)(ws + 176553984ull);  // 512KB
    bf16_t* W2_p    = (bf16_t*)(ws + 177078272ull);  // 512KB
    float*  el      = (float*) (ws + 177602560ull);  // 512KB
    float*  er      = (float*) (ws + 178126848ull);  // 512KB
    float*  ce      = (float*) (ws + 178651136ull);  // 16B
    int*    cursor  = (int*)   (ws + 178651200ull);  // 128KB

    if (ws_size < 180224064ull) return;

    hipMemsetAsync(cursor, 0, 131072, stream);

    // conversions / packing
    f2b_kernel<<<4096, 256, 0, stream>>>(h, hb);
    pack_b<<<32, 256, 0, stream>>>(W_fc, Wfc_p, 16, 512);
    pack_b<<<32, 256, 0, stream>>>(W_res, Wres_p, 16, 512);
    pack_b<<<32, 256, 0, stream>>>(W_mha, Wmha_p, 64, 128);
    pack_b<<<128, 256, 0, stream>>>(W1, W1_p, 16, 2048);
    pack_b<<<128, 256, 0, stream>>>(W2, W2_p, 256, 128);

    // ft = hb @ W_fc ; res = hb @ W_res
    gemm_mfma<bf16_t, false, false><<<dim3(4, 256), 256, 0, stream>>>(hb, Wfc_p, nullptr, ft, N_NODES, FDIM, 128);
    gemm_mfma<bf16_t, false, false><<<dim3(4, 256), 256, 0, stream>>>(hb, Wres_p, nullptr, res, N_NODES, FDIM, 128);
    attn_dots_kernel<<<N_NODES, 128, 0, stream>>>(ft, attn_l, attn_r, el, er);
    ce_kernel<<<1, 128, 0, stream>>>(W_fe, attn_e, ce);
    edge_build<<<E_EDGES / 256, 256, 0, stream>>>(evals, src, dst, el, er, ce, cursor, csr_src, csr_w);
    aggregate_kernel<<<N_NODES, 128, 0, stream>>>(ft, res, cursor, csr_src, csr_w, gat_bias, x1);
    // x2 = x1 @ W_mha + b_mha
    gemm_mfma<float, false, true><<<dim3(1, 256), 256, 0, stream>>>(x1, Wmha_p, b_mha, x2, N_NODES, 128, FDIM);
    ln_kernel<true, float, bf16_t><<<N_NODES, 128, 0, stream>>>(x2, h, n1_g, n1_b, x3b);
    // FFN
    gemm_mfma<bf16_t, true, true><<<dim3(16, 256), 256, 0, stream>>>(x3b, W1_p, b1, y, N_NODES, DFF, 128);
    gemm_mfma<float, false, true><<<dim3(1, 256), 256, 0, stream>>>(y, W2_p, b2, x2, N_NODES, 128, DFF);
    ln_kernel<false, bf16_t, float><<<N_NODES, 128, 0, stream>>>(x2, x3b, n2_g, n2_b, (float*)d_out);
}

// Round 5
// 315.839 us; speedup vs baseline: 3.6759x; 1.3349x over previous
//
#include <hip/hip_runtime.h>
#include <hip/hip_bf16.h>

#define N_NODES 32768
#define E_EDGES 524288
#define HIDDIM 128
#define FDIM 512
#define DFF 2048
#define LN_EPS 1e-5f
#define SLOPE 0.2f
#define CAP 64          // CSR slot capacity per dst (Poisson(16): P(>64) ~ 1e-19)

typedef __bf16 bf16_t;
typedef __bf16 bf16x8 __attribute__((ext_vector_type(8)));
typedef float f32x4 __attribute__((ext_vector_type(4)));
typedef float f32x2 __attribute__((ext_vector_type(2)));

#define GLD_LDS16(gp, lp) __builtin_amdgcn_global_load_lds( \
    (const __attribute__((address_space(1))) unsigned int*)(gp), \
    (__attribute__((address_space(3))) unsigned int*)(lp), 16, 0, 0)

// ---------- fp8 e4m3 codec (HW cvt when available) ----------
__device__ inline unsigned char f32_to_e4m3(float v) {
#if __has_builtin(__builtin_amdgcn_cvt_pk_fp8_f32)
    return (unsigned char)(__builtin_amdgcn_cvt_pk_fp8_f32(v, v, 0, false) & 0xff);
#else
    unsigned bits = __float_as_uint(v);
    unsigned sign = (bits >> 24) & 0x80;
    float av = fabsf(v);
    if (av >= 448.f) return (unsigned char)(sign | 0x7E);
    int e = (int)((bits >> 23) & 0xFF) - 127;
    if (e < -6) { int n = (int)rintf(av * 512.f); return (unsigned char)(sign | n); }
    float ulp = exp2f((float)(e - 3));
    int n = (int)rintf(av / ulp);
    if (n == 16) { e += 1; n = 8; }
    return (unsigned char)(sign | ((e + 7) << 3) | (n - 8));
#endif
}
template<bool HI>
__device__ inline f32x2 e4m3x2_to_f32(unsigned u) {
#if __has_builtin(__builtin_amdgcn_cvt_pk_f32_fp8)
    return __builtin_amdgcn_cvt_pk_f32_fp8(u, HI);
#else
    f32x2 r;
    unsigned b0 = HI ? ((u >> 16) & 0xff) : (u & 0xff);
    unsigned b1 = HI ? ((u >> 24) & 0xff) : ((u >> 8) & 0xff);
    unsigned bs[2] = {b0, b1};
    for (int i = 0; i < 2; ++i) {
        unsigned b = bs[i];
        float s = (b & 0x80) ? -1.f : 1.f;
        int e = (b >> 3) & 15, m = b & 7;
        float v = e ? (8 + m) * exp2f((float)(e - 10)) : m * exp2f(-9.f);
        r[i] = s * v;
    }
    return r;
#endif
}

// ============ generic bf16 MFMA GEMM (used for res): C bf16 = A @ Bp ============
// Bp k8-packed: Bp[((k/8)*N + n)*8 + j] = B[(k/8)*8+j][n]. 128x128 tile, 4 waves, BK=32.
__global__ __launch_bounds__(256) void gemm_mfma(const bf16_t* __restrict__ A,
                                                 const bf16_t* __restrict__ Bp,
                                                 bf16_t* __restrict__ C,
                                                 int M, int N, int K) {
    __shared__ __align__(16) bf16_t lA[4096];
    __shared__ __align__(16) bf16_t lB[4096];
    const int tid = threadIdx.x;
    const int lane = tid & 63;
    const int wave = tid >> 6;
    const int wm = (wave >> 1) * 64, wn = (wave & 1) * 64;
    const int row0 = blockIdx.y * 128, col0 = blockIdx.x * 128;
    const int ko = lane >> 4;
    const int rl = lane & 15;
    f32x4 acc[4][4] = {};
    const int c0 = tid, c1 = tid + 256;
    const int g0 = c0 >> 7, m0 = c0 & 127;
    const int g1 = c1 >> 7, m1 = c1 & 127;
    for (int k0 = 0; k0 < K; k0 += 32) {
        __syncthreads();
        GLD_LDS16(A + (size_t)(row0 + m0) * K + k0 + g0 * 8, lA + c0 * 8);
        GLD_LDS16(A + (size_t)(row0 + m1) * K + k0 + g1 * 8, lA + c1 * 8);
        GLD_LDS16(Bp + ((size_t)(k0 / 8 + g0) * N + col0 + m0) * 8, lB + c0 * 8);
        GLD_LDS16(Bp + ((size_t)(k0 / 8 + g1) * N + col0 + m1) * 8, lB + c1 * 8);
        __syncthreads();
        bf16x8 af[4], bfr[4];
#pragma unroll
        for (int i = 0; i < 4; ++i) {
            af[i]  = *(const bf16x8*)&lA[(ko * 128 + wm + i * 16 + rl) * 8];
            bfr[i] = *(const bf16x8*)&lB[(ko * 128 + wn + i * 16 + rl) * 8];
        }
#pragma unroll
        for (int i = 0; i < 4; ++i)
#pragma unroll
            for (int j = 0; j < 4; ++j)
                acc[i][j] = __builtin_amdgcn_mfma_f32_16x16x32_bf16(af[i], bfr[j], acc[i][j], 0, 0, 0);
    }
    const int cr = (lane >> 4) * 4;
    const int cc = lane & 15;
#pragma unroll
    for (int i = 0; i < 4; ++i)
#pragma unroll
        for (int j = 0; j < 4; ++j) {
            const int col = col0 + wn + j * 16 + cc;
#pragma unroll
            for (int r = 0; r < 4; ++r) {
                const int row = row0 + wm + i * 16 + cr + r;
                C[(size_t)row * N + col] = (bf16_t)acc[i][j][r];
            }
        }
}

// ============ ft GEMM: hb @ Wfc_p -> ft8 (fp8) + fused el/er head-dots ============
// grid (4, 256): blockIdx.x = head (col tile 128 = one head), K=128, N=512.
__global__ __launch_bounds__(256) void gemm_ft(const bf16_t* __restrict__ A,
                                               const bf16_t* __restrict__ Bp,
                                               const float* __restrict__ attn_l,
                                               const float* __restrict__ attn_r,
                                               unsigned char* __restrict__ ft8,
                                               float* __restrict__ el,
                                               float* __restrict__ er) {
    __shared__ __align__(16) bf16_t lA[4096];
    __shared__ __align__(16) bf16_t lB[4096];
    __shared__ float s_el[2][128], s_er[2][128];
    const int tid = threadIdx.x, lane = tid & 63, wave = tid >> 6;
    const int wm = (wave >> 1) * 64, wn = (wave & 1) * 64;
    const int row0 = blockIdx.y * 128;
    const int head = blockIdx.x, col0 = head * 128;
    const int ko = lane >> 4, rl = lane & 15;
    f32x4 acc[4][4] = {};
    const int c0 = tid, c1 = tid + 256;
    const int g0 = c0 >> 7, m0 = c0 & 127;
    const int g1 = c1 >> 7, m1 = c1 & 127;
    for (int k0 = 0; k0 < 128; k0 += 32) {
        __syncthreads();
        GLD_LDS16(A + (size_t)(row0 + m0) * 128 + k0 + g0 * 8, lA + c0 * 8);
        GLD_LDS16(A + (size_t)(row0 + m1) * 128 + k0 + g1 * 8, lA + c1 * 8);
        GLD_LDS16(Bp + ((size_t)(k0 / 8 + g0) * 512 + col0 + m0) * 8, lB + c0 * 8);
        GLD_LDS16(Bp + ((size_t)(k0 / 8 + g1) * 512 + col0 + m1) * 8, lB + c1 * 8);
        __syncthreads();
        bf16x8 af[4], bfr[4];
#pragma unroll
        for (int i = 0; i < 4; ++i) {
            af[i]  = *(const bf16x8*)&lA[(ko * 128 + wm + i * 16 + rl) * 8];
            bfr[i] = *(const bf16x8*)&lB[(ko * 128 + wn + i * 16 + rl) * 8];
        }
#pragma unroll
        for (int i = 0; i < 4; ++i)
#pragma unroll
            for (int j = 0; j < 4; ++j)
                acc[i][j] = __builtin_amdgcn_mfma_f32_16x16x32_bf16(af[i], bfr[j], acc[i][j], 0, 0, 0);
    }
    const int cr = (lane >> 4) * 4, cc = lane & 15;
    float al[4], ar[4];
#pragma unroll
    for (int j = 0; j < 4; ++j) {
        al[j] = attn_l[col0 + wn + j * 16 + cc];
        ar[j] = attn_r[col0 + wn + j * 16 + cc];
    }
#pragma unroll
    for (int i = 0; i < 4; ++i)
#pragma unroll
        for (int r = 0; r < 4; ++r) {
            const int row = row0 + wm + i * 16 + cr + r;
            float pel = 0.f, per = 0.f;
#pragma unroll
            for (int j = 0; j < 4; ++j) {
                const float v = acc[i][j][r];
                ft8[(size_t)row * 512 + col0 + wn + j * 16 + cc] = f32_to_e4m3(v);
                pel += v * al[j];
                per += v * ar[j];
            }
#pragma unroll
            for (int m = 1; m < 16; m <<= 1) {
                pel += __shfl_xor(pel, m);
                per += __shfl_xor(per, m);
            }
            if (cc == 0) {
                s_el[wn >> 6][wm + i * 16 + cr + r] = pel;
                s_er[wn >> 6][wm + i * 16 + cr + r] = per;
            }
        }
    __syncthreads();
    if (tid < 128) {
        el[(size_t)(row0 + tid) * 4 + head] = s_el[0][tid] + s_el[1][tid];
        er[(size_t)(row0 + tid) * 4 + head] = s_er[0][tid] + s_er[1][tid];
    }
}

// ============ mha GEMM + LN1 fused: x3b = LN(h + relu(x1 @ Wmha + b_mha)) ============
// grid (256): 128-row tiles, N=128, K=512.
__global__ __launch_bounds__(256) void gemm_mha_ln(const bf16_t* __restrict__ A,
                                                   const bf16_t* __restrict__ Bp,
                                                   const float* __restrict__ bias,
                                                   const float* __restrict__ h0,
                                                   const float* __restrict__ gamma,
                                                   const float* __restrict__ beta,
                                                   bf16_t* __restrict__ out) {
    __shared__ __align__(16) bf16_t lA[4096];
    __shared__ __align__(16) bf16_t lB[4096];
    __shared__ float s_s1[2][128], s_s2[2][128], s_mu[128], s_rs[128];
    const int tid = threadIdx.x, lane = tid & 63, wave = tid >> 6;
    const int wm = (wave >> 1) * 64, wn = (wave & 1) * 64;
    const int row0 = blockIdx.x * 128;
    const int ko = lane >> 4, rl = lane & 15;
    f32x4 acc[4][4] = {};
    const int c0 = tid, c1 = tid + 256;
    const int g0 = c0 >> 7, m0 = c0 & 127;
    const int g1 = c1 >> 7, m1 = c1 & 127;
    for (int k0 = 0; k0 < 512; k0 += 32) {
        __syncthreads();
        GLD_LDS16(A + (size_t)(row0 + m0) * 512 + k0 + g0 * 8, lA + c0 * 8);
        GLD_LDS16(A + (size_t)(row0 + m1) * 512 + k0 + g1 * 8, lA + c1 * 8);
        GLD_LDS16(Bp + ((size_t)(k0 / 8 + g0) * 128 + m0) * 8, lB + c0 * 8);
        GLD_LDS16(Bp + ((size_t)(k0 / 8 + g1) * 128 + m1) * 8, lB + c1 * 8);
        __syncthreads();
        bf16x8 af[4], bfr[4];
#pragma unroll
        for (int i = 0; i < 4; ++i) {
            af[i]  = *(const bf16x8*)&lA[(ko * 128 + wm + i * 16 + rl) * 8];
            bfr[i] = *(const bf16x8*)&lB[(ko * 128 + wn + i * 16 + rl) * 8];
        }
#pragma unroll
        for (int i = 0; i < 4; ++i)
#pragma unroll
            for (int j = 0; j < 4; ++j)
                acc[i][j] = __builtin_amdgcn_mfma_f32_16x16x32_bf16(af[i], bfr[j], acc[i][j], 0, 0, 0);
    }
    const int cr = (lane >> 4) * 4, cc = lane & 15;
    // x = relu(acc + bias) + h ; keep in acc
#pragma unroll
    for (int j = 0; j < 4; ++j) {
        const int col = wn + j * 16 + cc;
        const float bb = bias[col];
#pragma unroll
        for (int i = 0; i < 4; ++i)
#pragma unroll
            for (int r = 0; r < 4; ++r) {
                const int row = row0 + wm + i * 16 + cr + r;
                acc[i][j][r] = fmaxf(acc[i][j][r] + bb, 0.f) + h0[(size_t)row * 128 + col];
            }
    }
    // row sums
#pragma unroll
    for (int i = 0; i < 4; ++i)
#pragma unroll
        for (int r = 0; r < 4; ++r) {
            float s1 = 0.f, s2 = 0.f;
#pragma unroll
            for (int j = 0; j < 4; ++j) { const float v = acc[i][j][r]; s1 += v; s2 += v * v; }
#pragma unroll
            for (int m = 1; m < 16; m <<= 1) {
                s1 += __shfl_xor(s1, m);
                s2 += __shfl_xor(s2, m);
            }
            if (cc == 0) {
                s_s1[wn >> 6][wm + i * 16 + cr + r] = s1;
                s_s2[wn >> 6][wm + i * 16 + cr + r] = s2;
            }
        }
    __syncthreads();
    if (tid < 128) {
        const float a = s_s1[0][tid] + s_s1[1][tid];
        const float q = s_s2[0][tid] + s_s2[1][tid];
        const float mu = a * (1.f / 128.f);
        s_mu[tid] = mu;
        s_rs[tid] = rsqrtf(q * (1.f / 128.f) - mu * mu + LN_EPS);
    }
    __syncthreads();
#pragma unroll
    for (int j = 0; j < 4; ++j) {
        const int col = wn + j * 16 + cc;
        const float gg = gamma[col], bb = beta[col];
#pragma unroll
        for (int i = 0; i < 4; ++i)
#pragma unroll
            for (int r = 0; r < 4; ++r) {
                const int rloc = wm + i * 16 + cr + r;
                out[(size_t)(row0 + rloc) * 128 + col] =
                    (bf16_t)((acc[i][j][r] - s_mu[rloc]) * s_rs[rloc] * gg + bb);
            }
    }
}

// ============ fused FFN + LN2: out = LN(x3 + (relu(x3@W1+b1))@W2 + b2) ============
// grid (256): 128-row tiles. y never hits HBM.
__global__ __launch_bounds__(256, 1) void ffn_fused(const bf16_t* __restrict__ x3,
                                                    const bf16_t* __restrict__ W1p,
                                                    const float* __restrict__ b1,
                                                    const bf16_t* __restrict__ W2p,
                                                    const float* __restrict__ b2,
                                                    const float* __restrict__ gamma,
                                                    const float* __restrict__ beta,
                                                    float* __restrict__ out) {
    __shared__ __align__(16) bf16_t lX[16384];   // 32KB (g*128+m)*8
    __shared__ __align__(16) bf16_t lW1[16384];  // 32KB
    __shared__ __align__(16) bf16_t lW2[16384];  // 32KB
    __shared__ __align__(16) bf16_t lY[16384];   // 32KB
    __shared__ float s_s1[2][128], s_s2[2][128], s_mu[128], s_rs[128];
    const int tid = threadIdx.x, lane = tid & 63, wave = tid >> 6;
    const int wm = (wave >> 1) * 64, wn = (wave & 1) * 64;
    const int row0 = blockIdx.x * 128;
    const int ko = lane >> 4, rl = lane & 15;
    const int cr = (lane >> 4) * 4, cc = lane & 15;
    // stage x3 tile (persistent)
#pragma unroll
    for (int it = 0; it < 8; ++it) {
        const int c = it * 256 + tid;
        const int g = c >> 7, m = c & 127;
        GLD_LDS16(x3 + (size_t)(row0 + m) * 128 + g * 8, lX + c * 8);
    }
    f32x4 xacc[4][4] = {};
    for (int ch = 0; ch < 16; ++ch) {
        __syncthreads();
#pragma unroll
        for (int it = 0; it < 8; ++it) {
            const int c = it * 256 + tid;
            const int g = c >> 7, n = c & 127;
            GLD_LDS16(W1p + ((size_t)g * 2048 + ch * 128 + n) * 8, lW1 + c * 8);
            GLD_LDS16(W2p + ((size_t)(ch * 16 + g) * 128 + n) * 8, lW2 + c * 8);
        }
        __syncthreads();
        f32x4 yacc[4][4] = {};
#pragma unroll
        for (int kk = 0; kk < 4; ++kk) {
            bf16x8 af[4], bfr[4];
#pragma unroll
            for (int i = 0; i < 4; ++i) {
                af[i]  = *(const bf16x8*)&lX[((kk * 4 + ko) * 128 + wm + i * 16 + rl) * 8];
                bfr[i] = *(const bf16x8*)&lW1[((kk * 4 + ko) * 128 + wn + i * 16 + rl) * 8];
            }
#pragma unroll
            for (int i = 0; i < 4; ++i)
#pragma unroll
                for (int j = 0; j < 4; ++j)
                    yacc[i][j] = __builtin_amdgcn_mfma_f32_16x16x32_bf16(af[i], bfr[j], yacc[i][j], 0, 0, 0);
        }
        // relu+bias -> lY (A-frag layout, k = chunk-local dff col)
#pragma unroll
        for (int j = 0; j < 4; ++j) {
            const int col = wn + j * 16 + cc;
            const float bb = b1[ch * 128 + col];
#pragma unroll
            for (int i = 0; i < 4; ++i)
#pragma unroll
                for (int r = 0; r < 4; ++r) {
                    const float v = fmaxf(yacc[i][j][r] + bb, 0.f);
                    const int row = wm + i * 16 + cr + r;
                    lY[((col >> 3) * 128 + row) * 8 + (col & 7)] = (bf16_t)v;
                }
        }
        __syncthreads();
#pragma unroll
        for (int kk = 0; kk < 4; ++kk) {
            bf16x8 af[4], bfr[4];
#pragma unroll
            for (int i = 0; i < 4; ++i) {
                af[i]  = *(const bf16x8*)&lY[((kk * 4 + ko) * 128 + wm + i * 16 + rl) * 8];
                bfr[i] = *(const bf16x8*)&lW2[((kk * 4 + ko) * 128 + wn + i * 16 + rl) * 8];
            }
#pragma unroll
            for (int i = 0; i < 4; ++i)
#pragma unroll
                for (int j = 0; j < 4; ++j)
                    xacc[i][j] = __builtin_amdgcn_mfma_f32_16x16x32_bf16(af[i], bfr[j], xacc[i][j], 0, 0, 0);
        }
    }
    // epilogue: + b2 + x3, LN2, store fp32
#pragma unroll
    for (int j = 0; j < 4; ++j) {
        const int col = wn + j * 16 + cc;
        const float bb = b2[col];
#pragma unroll
        for (int i = 0; i < 4; ++i)
#pragma unroll
            for (int r = 0; r < 4; ++r) {
                const int row = wm + i * 16 + cr + r;
                const float x3v = (float)lX[((col >> 3) * 128 + row) * 8 + (col & 7)];
                xacc[i][j][r] += bb + x3v;
            }
    }
#pragma unroll
    for (int i = 0; i < 4; ++i)
#pragma unroll
        for (int r = 0; r < 4; ++r) {
            float s1 = 0.f, s2 = 0.f;
#pragma unroll
            for (int j = 0; j < 4; ++j) { const float v = xacc[i][j][r]; s1 += v; s2 += v * v; }
#pragma unroll
            for (int m = 1; m < 16; m <<= 1) {
                s1 += __shfl_xor(s1, m);
                s2 += __shfl_xor(s2, m);
            }
            if (cc == 0) {
                s_s1[wn >> 6][wm + i * 16 + cr + r] = s1;
                s_s2[wn >> 6][wm + i * 16 + cr + r] = s2;
            }
        }
    __syncthreads();
    if (tid < 128) {
        const float a = s_s1[0][tid] + s_s1[1][tid];
        const float q = s_s2[0][tid] + s_s2[1][tid];
        const float mu = a * (1.f / 128.f);
        s_mu[tid] = mu;
        s_rs[tid] = rsqrtf(q * (1.f / 128.f) - mu * mu + LN_EPS);
    }
    __syncthreads();
#pragma unroll
    for (int j = 0; j < 4; ++j) {
        const int col = wn + j * 16 + cc;
        const float gg = gamma[col], bb = beta[col];
#pragma unroll
        for (int i = 0; i < 4; ++i)
#pragma unroll
            for (int r = 0; r < 4; ++r) {
                const int rloc = wm + i * 16 + cr + r;
                out[(size_t)(row0 + rloc) * 128 + col] =
                    (xacc[i][j][r] - s_mu[rloc]) * s_rs[rloc] * gg + bb;
            }
    }
}

// ============ weight packing: fp32 [K][N] -> k8-packed bf16 ============
__global__ __launch_bounds__(256) void pack_b(const float* __restrict__ B, bf16_t* __restrict__ out,
                                              int K8, int N) {
    const int id = blockIdx.x * 256 + threadIdx.x;
    if (id >= K8 * N) return;
    const int g = id / N, n = id % N;
    union { bf16_t b[8]; uint4 u; } pk;
#pragma unroll
    for (int j = 0; j < 8; ++j) pk.b[j] = (bf16_t)B[(size_t)(g * 8 + j) * N + n];
    *(uint4*)(out + (size_t)id * 8) = pk.u;
}

__global__ __launch_bounds__(256) void f2b_kernel(const float* __restrict__ x, bf16_t* __restrict__ o) {
    const int id = blockIdx.x * 256 + threadIdx.x;
    const float4 v = ((const float4*)x)[id];
    union { bf16_t b[4]; uint2 u; } pk;
    pk.b[0] = (bf16_t)v.x; pk.b[1] = (bf16_t)v.y; pk.b[2] = (bf16_t)v.z; pk.b[3] = (bf16_t)v.w;
    *(uint2*)(o + (size_t)id * 4) = pk.u;
}

__global__ __launch_bounds__(128) void ce_kernel(const float* __restrict__ W_fe,
                                                 const float* __restrict__ attn_e,
                                                 float* __restrict__ ce) {
    const int t = threadIdx.x;
    const float4 w = ((const float4*)W_fe)[t];
    const float4 a = ((const float4*)attn_e)[t];
    float p = w.x * a.x + w.y * a.y + w.z * a.z + w.w * a.w;
    for (int off = 16; off; off >>= 1) p += __shfl_down(p, off, 32);
    if ((t & 31) == 0) ce[t >> 5] = p;
}

// ============ edge build: w = exp(leaky(score)); scatter into CSR slots ============
__global__ __launch_bounds__(256) void edge_build(const float* __restrict__ evals,
                                                  const int* __restrict__ src,
                                                  const int* __restrict__ dst,
                                                  const float* __restrict__ el,
                                                  const float* __restrict__ er,
                                                  const float* __restrict__ ce,
                                                  int* __restrict__ cursor,
                                                  int* __restrict__ csr_src,
                                                  float4* __restrict__ csr_w) {
    const int e = blockIdx.x * 256 + threadIdx.x;
    const int s = src[e], d = dst[e];
    const float ev = evals[e];
    const float4 l = *(const float4*)(el + (size_t)s * 4);
    const float4 r = *(const float4*)(er + (size_t)d * 4);
    const float4 c = *(const float4*)ce;
    float4 w;
    {
        float v;
        v = l.x + r.x + ev * c.x; v = v >= 0.f ? v : SLOPE * v; w.x = expf(v);
        v = l.y + r.y + ev * c.y; v = v >= 0.f ? v : SLOPE * v; w.y = expf(v);
        v = l.z + r.z + ev * c.z; v = v >= 0.f ? v : SLOPE * v; w.z = expf(v);
        v = l.w + r.w + ev * c.w; v = v >= 0.f ? v : SLOPE * v; w.w = expf(v);
    }
    const int pos = atomicAdd(&cursor[d], 1);
    if (pos < CAP) {
        csr_src[(size_t)d * CAP + pos] = s;
        csr_w[(size_t)d * CAP + pos] = w;
    }
}

// ============ aggregate (fp8 gather): x1 = relu((Σ w*ft[src])/Σw + res + bias) ============
__global__ __launch_bounds__(128) void aggregate_kernel(const unsigned char* __restrict__ ft8,
                                                        const bf16_t* __restrict__ res,
                                                        const int* __restrict__ cursor,
                                                        const int* __restrict__ csr_src,
                                                        const float4* __restrict__ csr_w,
                                                        const float* __restrict__ gat_bias,
                                                        bf16_t* __restrict__ x1) {
    const int n = blockIdx.x, t = threadIdx.x;
    __shared__ int s_src[CAP];
    __shared__ float s_w[CAP][4];
    const int deg = min(cursor[n], CAP);
    const int ht = t >> 5;
    if (t < deg) {
        s_src[t] = csr_src[(size_t)n * CAP + t];
        *(float4*)s_w[t] = csr_w[(size_t)n * CAP + t];
    }
    __syncthreads();
    float4 acc = {0.f, 0.f, 0.f, 0.f};
    float z = 0.f;
    for (int j = 0; j < deg; ++j) {
        const float w = s_w[j][ht];
        z += w;
        const unsigned u = *(const unsigned*)(ft8 + (size_t)s_src[j] * 512 + t * 4);
        const f32x2 lo = e4m3x2_to_f32<false>(u);
        const f32x2 hi = e4m3x2_to_f32<true>(u);
        acc.x += w * lo[0]; acc.y += w * lo[1];
        acc.z += w * hi[0]; acc.w += w * hi[1];
    }
    const float rz = deg > 0 ? 1.f / z : 0.f;
    const uint2 ur = *(const uint2*)(res + (size_t)n * FDIM + t * 4);
    const float4 gb = ((const float4*)gat_bias)[t];
    union { bf16_t b[4]; uint2 u; } pk;
    pk.b[0] = (bf16_t)fmaxf(acc.x * rz + __uint_as_float(ur.x << 16) + gb.x, 0.f);
    pk.b[1] = (bf16_t)fmaxf(acc.y * rz + __uint_as_float(ur.x & 0xFFFF0000u) + gb.y, 0.f);
    pk.b[2] = (bf16_t)fmaxf(acc.z * rz + __uint_as_float(ur.y << 16) + gb.z, 0.f);
    pk.b[3] = (bf16_t)fmaxf(acc.w * rz + __uint_as_float(ur.y & 0xFFFF0000u) + gb.w, 0.f);
    *(uint2*)(x1 + (size_t)n * FDIM + t * 4) = pk.u;
}

extern "C" void kernel_launch(void* const* d_in, const int* in_sizes, int n_in,
                              void* d_out, int out_size, void* d_ws, size_t ws_size,
                              hipStream_t stream) {
    const float* h        = (const float*)d_in[0];
    const float* evals    = (const float*)d_in[1];
    const int*   src      = (const int*)d_in[2];
    const int*   dst      = (const int*)d_in[3];
    const float* W_fc     = (const float*)d_in[5];
    const float* attn_l   = (const float*)d_in[6];
    const float* attn_r   = (const float*)d_in[7];
    const float* W_fe     = (const float*)d_in[8];
    const float* attn_e   = (const float*)d_in[9];
    const float* W_res    = (const float*)d_in[10];
    const float* gat_bias = (const float*)d_in[11];
    const float* W_mha    = (const float*)d_in[12];
    const float* b_mha    = (const float*)d_in[13];
    const float* n1_g     = (const float*)d_in[14];
    const float* n1_b     = (const float*)d_in[15];
    const float* n2_g     = (const float*)d_in[16];
    const float* n2_b     = (const float*)d_in[17];
    const float* W1       = (const float*)d_in[18];
    const float* b1       = (const float*)d_in[19];
    const float* W2       = (const float*)d_in[20];
    const float* b2       = (const float*)d_in[21];

    char* ws = (char*)d_ws;
    unsigned char* ft8 = (unsigned char*)(ws + 0);   // 16MB  N x 512 fp8
    bf16_t* res     = (bf16_t*)(ws + 16777216ull);   // 32MB  N x 512
    bf16_t* x1      = (bf16_t*)(ws + 50331648ull);   // 32MB  N x 512
    float4* csr_w   = (float4*)(ws + 83886080ull);   // 32MB  N x CAP x 16B
    int*    csr_src = (int*)   (ws + 117440512ull);  // 8MB   N x CAP
    bf16_t* x3b     = (bf16_t*)(ws + 125829120ull);  // 8MB   N x 128
    bf16_t* hb      = (bf16_t*)(ws + 134217728ull);  // 8MB   N x 128
    bf16_t* Wfc_p   = (bf16_t*)(ws + 142606336ull);  // 128KB
    bf16_t* Wres_p  = (bf16_t*)(ws + 142737408ull);  // 128KB
    bf16_t* Wmha_p  = (bf16_t*)(ws + 142868480ull);  // 128KB
    bf16_t* W1_p    = (bf16_t*)(ws + 142999552ull);  // 512KB
    bf16_t* W2_p    = (bf16_t*)(ws + 143523840ull);  // 512KB
    float*  el      = (float*) (ws + 144048128ull);  // 512KB
    float*  er      = (float*) (ws + 144572416ull);  // 512KB
    float*  ce      = (float*) (ws + 145096704ull);  // 16B
    int*    cursor  = (int*)   (ws + 145096768ull);  // 128KB

    if (ws_size < 146000000ull) return;

    (void)hipMemsetAsync(cursor, 0, 131072, stream);

    f2b_kernel<<<4096, 256, 0, stream>>>(h, hb);
    pack_b<<<32, 256, 0, stream>>>(W_fc, Wfc_p, 16, 512);
    pack_b<<<32, 256, 0, stream>>>(W_res, Wres_p, 16, 512);
    pack_b<<<32, 256, 0, stream>>>(W_mha, Wmha_p, 64, 128);
    pack_b<<<128, 256, 0, stream>>>(W1, W1_p, 16, 2048);
    pack_b<<<128, 256, 0, stream>>>(W2, W2_p, 256, 128);
    ce_kernel<<<1, 128, 0, stream>>>(W_fe, attn_e, ce);

    gemm_ft<<<dim3(4, 256), 256, 0, stream>>>(hb, Wfc_p, attn_l, attn_r, ft8, el, er);
    gemm_mfma<<<dim3(4, 256), 256, 0, stream>>>(hb, Wres_p, res, N_NODES, FDIM, 128);
    edge_build<<<E_EDGES / 256, 256, 0, stream>>>(evals, src, dst, el, er, ce, cursor, csr_src, csr_w);
    aggregate_kernel<<<N_NODES, 128, 0, stream>>>(ft8, res, cursor, csr_src, csr_w, gat_bias, x1);
    gemm_mha_ln<<<256, 256, 0, stream>>>(x1, Wmha_p, b_mha, h, n1_g, n1_b, x3b);
    ffn_fused<<<256, 256, 0, stream>>>(x3b, W1_p, b1, W2_p, b2, n2_g, n2_b, (float*)d_out);
}